// Round 10
// baseline (776.999 us; speedup 1.0000x reference)
//
#include <hip/hip_runtime.h>
#include <stdint.h>

#define D_DIM 1024
#define M_TOT 16384        // rows per stream (8*2048)
#define M2 32768           // fused enc+tgt rows
#define N_LAYERS 3
#define NT 16              // K tiles (K=1024 / BK=64)

typedef unsigned short u16;
typedef __attribute__((ext_vector_type(8))) short bf16x8;
typedef __attribute__((ext_vector_type(4))) float f32x4;
typedef __attribute__((ext_vector_type(4))) unsigned short u16x4;
typedef __attribute__((ext_vector_type(8))) unsigned short u16x8;

typedef __attribute__((address_space(1))) void gvoid_t;
typedef __attribute__((address_space(3))) void lvoid_t;

__device__ __forceinline__ float b2f(u16 u) {
  union { unsigned int i; float f; } x; x.i = ((unsigned int)u) << 16; return x.f;
}
__device__ __forceinline__ u16 f2b(float f) {  // RNE f32 -> bf16
  union { float f; unsigned int i; } x; x.f = f;
  unsigned int r = x.i + 0x7fffu + ((x.i >> 16) & 1u);
  return (u16)(r >> 16);
}

__device__ __forceinline__ void gload_lds16(const void* g, void* l) {
  __builtin_amdgcn_global_load_lds((gvoid_t*)(uintptr_t)g,
                                   (lvoid_t*)(unsigned int)(uintptr_t)l, 16, 0, 0);
}

// ---------------------------------------------------------------------------
// m97-exact GEMM engine (R9-verified: 820 TF, 0 bank conflicts): 128x128 tile,
// BK=64, 256 thr (2x2 waves, 4x4 frags of 16x16x32), SINGLE 32KB LDS buffer,
// plain 2-barrier K-loop, plain C++ LDS reads. Mechanism: blocks/CU
// co-residency gives cross-block DS||MFMA||HBM overlap (m114/m97).
// launch_bounds(256,5): 5 blocks/CU (5x32KB = 160KB LDS, VGPR 56 << 102).
// B row-major [N x K] (B^T GEMM). Grid: bmT = wg>>nsh, bnT = wg&((1<<nsh)-1).
// EPI 0: outB = bf16(sigmoid(acc+bias) * xfB * decay)
// EPI 1: outB = bf16(acc + bias + xfB)              (pre-LN)
// EPI 5: fused MoE over interleaved Wcat (col n = f*4+e):
//        v = probs[m,e]*(acc + exp_b[e*1024+f]); nibble shfl-sum over e;
//        lane (lm&3)==0 writes outF[m][f]  (full f32 combine).
// ---------------------------------------------------------------------------
template <int EPI>
__global__ __launch_bounds__(256, 5) void gemm97(
    const u16* __restrict__ A,
    const u16* __restrict__ B_a, const u16* __restrict__ B_b,
    const float* __restrict__ bias_a, const float* __restrict__ bias_b,
    const float* __restrict__ dec_a, const float* __restrict__ dec_b,
    const u16* __restrict__ xfB, const float* __restrict__ probs,
    int mTiles, int nsh, int split,
    u16* __restrict__ outB, float* __restrict__ outF)
{
  __shared__ __align__(128) u16 lds[16384];   // 32KB: A[128][64] @0, B @16KB
  const char* ldsc = (const char*)lds;
  int t = threadIdx.x;
  int wid = t >> 6, l = t & 63;
  int wm = wid >> 1, wn = wid & 1;            // 2x2 waves; wave tile 64x64
  int lm = l & 15, g = l >> 4;

  int nwg = mTiles << nsh;
  int orig = blockIdx.x;
  int wg = (orig & 7) * (nwg >> 3) + (orig >> 3);   // bijective (nwg % 8 == 0)
  int bmT = wg >> nsh, bnT = wg & ((1 << nsh) - 1);
  int bm0 = bmT << 7, bn0 = bnT << 7;

  const u16*  Bm   = (bmT < split) ? B_a   : B_b;
  const float* bias = (bmT < split) ? bias_a : bias_b;
  const float* dec  = (bmT < split) ? dec_a  : dec_b;

  // staging: 8 threads per 128B row (16B each), 32 rows/round, 4 rounds/matrix.
  // physical chunk q holds logical chunk q ^ (row&7)  (pre-swizzled source).
  int rowS = t >> 3;                          // 0..31
  int colE = ((t & 7) ^ (rowS & 7)) << 3;     // element col within 64-elem row
  const u16* pA = A  + (size_t)(bm0 + rowS) * D_DIM + colE;
  const u16* pB = Bm + (size_t)(bn0 + rowS) * D_DIM + colE;
  u16* dW = lds + wid * 512;                  // wave-uniform dst (lane*16B implicit)

  f32x4 acc[4][4];
#pragma unroll
  for (int mi = 0; mi < 4; mi++)
#pragma unroll
    for (int ni = 0; ni < 4; ni++) acc[mi][ni] = 0.0f;

  // read-side swizzled k-col byte offsets: logical chunk = ks*4+g, ^ (lm&7)
  unsigned kc0 = (unsigned)(((0 * 4 + g) ^ (lm & 7)) << 4);
  unsigned kc1 = (unsigned)(((1 * 4 + g) ^ (lm & 7)) << 4);
  unsigned rbA = (unsigned)((wm * 64 + lm) * 128);
  unsigned rbB = (unsigned)(16384 + (wn * 64 + lm) * 128);

  for (int kt = 0; kt < NT; ++kt) {
    // ---- stage tile kt (single buffer) ----
    {
      const u16* a0 = pA + kt * 64;
      const u16* b0 = pB + kt * 64;
#pragma unroll
      for (int r = 0; r < 4; r++) {
        gload_lds16(a0 + (size_t)r * 32 * D_DIM, dW + r * 2048);
        gload_lds16(b0 + (size_t)r * 32 * D_DIM, dW + 8192 + r * 2048);
      }
    }
    __syncthreads();    // compiler: s_waitcnt vmcnt(0) lgkmcnt(0) + s_barrier
    // ---- compute tile kt ----
#pragma unroll
    for (int ks = 0; ks < 2; ks++) {
      unsigned kc = ks ? kc1 : kc0;
      bf16x8 av[4], bv[4];
#pragma unroll
      for (int mi = 0; mi < 4; mi++)
        av[mi] = *(const bf16x8*)(ldsc + rbA + mi * 2048 + kc);
#pragma unroll
      for (int ni = 0; ni < 4; ni++)
        bv[ni] = *(const bf16x8*)(ldsc + rbB + ni * 2048 + kc);
#pragma unroll
      for (int mi = 0; mi < 4; mi++)
#pragma unroll
        for (int ni = 0; ni < 4; ni++)
          acc[mi][ni] = __builtin_amdgcn_mfma_f32_16x16x32_bf16(av[mi], bv[ni], acc[mi][ni], 0, 0, 0);
    }
    __syncthreads();    // reads done before next stage overwrites
  }

  // ---- epilogue ----  m = bm0+wm*64+mi*16+g*4+j, n = bn0+wn*64+ni*16+lm
  int nidx[4]; float bia[4], dcv[4];
#pragma unroll
  for (int ni = 0; ni < 4; ni++) {
    nidx[ni] = bn0 + wn * 64 + ni * 16 + lm;
    if (EPI == 5) bia[ni] = bias[(nidx[ni] & 3) * 1024 + (nidx[ni] >> 2)];
    else          bia[ni] = bias[nidx[ni]];
    dcv[ni] = (EPI == 0) ? dec[nidx[ni]] : 0.0f;
  }
#pragma unroll
  for (int mi = 0; mi < 4; mi++)
#pragma unroll
    for (int j = 0; j < 4; j++) {
      size_t m = (size_t)bm0 + wm * 64 + mi * 16 + g * 4 + j;
      if (EPI == 0) {
        const u16* xr = xfB + m * D_DIM;
        u16* orow = outB + m * D_DIM;
#pragma unroll
        for (int ni = 0; ni < 4; ni++) {
          float v = acc[mi][ni][j] + bia[ni];
          float gt = 1.0f / (1.0f + __expf(-v));
          orow[nidx[ni]] = f2b(gt * b2f(xr[nidx[ni]]) * dcv[ni]);
        }
      } else if (EPI == 1) {
        const u16* xr = xfB + m * D_DIM;
        u16* orow = outB + m * D_DIM;
#pragma unroll
        for (int ni = 0; ni < 4; ni++)
          orow[nidx[ni]] = f2b(acc[mi][ni][j] + bia[ni] + b2f(xr[nidx[ni]]));
      } else {
        // EPI 5: e = nidx&3 == lm&3 (bn0, wn*64, ni*16 all multiples of 4)
        float p = probs[m * 4 + (lm & 3)];
        float* orow = outF + m * D_DIM;
#pragma unroll
        for (int ni = 0; ni < 4; ni++) {
          float v = p * (acc[mi][ni][j] + bia[ni]);
          v += __shfl_xor(v, 1);
          v += __shfl_xor(v, 2);
          if ((lm & 3) == 0) orow[nidx[ni] >> 2] = v;
        }
      }
    }
}

// Fused-stack LayerNorm over D=1024 (rows<M_TOT -> tgt params, else enc).
__global__ __launch_bounds__(256) void ln_fused(const u16* __restrict__ src,
                                                const float* __restrict__ gamT,
                                                const float* __restrict__ betT,
                                                const float* __restrict__ gamE,
                                                const float* __restrict__ betE,
                                                float* __restrict__ dstF,
                                                u16* __restrict__ dstB) {
  size_t row = blockIdx.x;
  const float* gamma = (row < M_TOT) ? gamT : gamE;
  const float* beta  = (row < M_TOT) ? betT : betE;
  int t = threadIdx.x, w = t >> 6, l = t & 63;
  u16x4 vb = ((const u16x4*)(src + row * D_DIM))[t];
  float v[4];
#pragma unroll
  for (int i = 0; i < 4; i++) v[i] = b2f(vb[i]);
  float s = v[0] + v[1] + v[2] + v[3];
  float qs = v[0]*v[0] + v[1]*v[1] + v[2]*v[2] + v[3]*v[3];
#pragma unroll
  for (int off = 32; off; off >>= 1) { s += __shfl_xor(s, off); qs += __shfl_xor(qs, off); }
  __shared__ float red[8];
  if (l == 0) { red[w] = s; red[4 + w] = qs; }
  __syncthreads();
  s = red[0] + red[1] + red[2] + red[3];
  qs = red[4] + red[5] + red[6] + red[7];
  float mu = s * (1.0f / 1024.0f);
  float var = qs * (1.0f / 1024.0f) - mu * mu;
  float inv = rsqrtf(var + 1e-5f);
  f32x4 gm = ((const f32x4*)gamma)[t], b = ((const f32x4*)beta)[t];
  f32x4 y; u16x4 yb;
#pragma unroll
  for (int i = 0; i < 4; i++) { y[i] = (v[i] - mu) * inv * gm[i] + b[i]; yb[i] = f2b(y[i]); }
  ((u16x4*)(dstB + row * D_DIM))[t] = yb;
  if (dstF != nullptr && row < M_TOT) ((f32x4*)(dstF + row * D_DIM))[t] = y;
}

// f32 -> bf16 elementwise
__global__ void conv_kernel(const float* __restrict__ src, u16* __restrict__ dst, int n4) {
  int i = blockIdx.x * 256 + threadIdx.x;
  if (i >= n4) return;
  f32x4 v = ((const f32x4*)src)[i];
  u16x4 o;
#pragma unroll
  for (int j = 0; j < 4; j++) o[j] = f2b(v[j]);
  ((u16x4*)dst)[i] = o;
}

// exp_W [4][1024][1024] f32 -> Wcat bf16 [4096][1024], row (f*4+e) = W_e[f][:]
__global__ void conv_wexp(const float* __restrict__ src, u16* __restrict__ dst) {
  int c = blockIdx.x * 256 + threadIdx.x;    // 524288 threads, 8 elems each
  int k8 = c & 127;
  int e  = (c >> 7) & 3;
  int f  = c >> 9;
  const float* s = src + ((size_t)e << 20) + (size_t)f * 1024 + k8 * 8;
  f32x4 v0 = ((const f32x4*)s)[0];
  f32x4 v1 = ((const f32x4*)s)[1];
  u16x8 o;
#pragma unroll
  for (int i = 0; i < 4; i++) { o[i] = f2b(v0[i]); o[4 + i] = f2b(v1[i]); }
  *(u16x8*)(dst + ((size_t)(f * 4 + e) << 10) + k8 * 8) = o;
}

// Gate: logits + softmax -> probs[m,0..3]. One wave per row.
__global__ __launch_bounds__(256) void gate_kernel(const u16* __restrict__ zb,
                                                   const float* __restrict__ gW,
                                                   const float* __restrict__ gb,
                                                   float* __restrict__ probs) {
  __shared__ float sW[4096];
  int t = threadIdx.x;
#pragma unroll
  for (int c = 0; c < 4; c++) ((f32x4*)sW)[c * 256 + t] = ((const f32x4*)gW)[c * 256 + t];
  __syncthreads();
  int w = t >> 6, l = t & 63;
  size_t m = (size_t)blockIdx.x * 4 + w;
  const u16* zr = zb + m * D_DIM;
  float d0 = 0, d1 = 0, d2 = 0, d3 = 0;
#pragma unroll
  for (int c = 0; c < 4; c++) {
    int k = l * 4 + c * 256;
    u16x4 zv = *(const u16x4*)(zr + k);
    f32x4 w0 = *(const f32x4*)&sW[k];
    f32x4 w1 = *(const f32x4*)&sW[1024 + k];
    f32x4 w2 = *(const f32x4*)&sW[2048 + k];
    f32x4 w3 = *(const f32x4*)&sW[3072 + k];
#pragma unroll
    for (int i = 0; i < 4; i++) {
      float zf = b2f(zv[i]);
      d0 += zf * w0[i]; d1 += zf * w1[i]; d2 += zf * w2[i]; d3 += zf * w3[i];
    }
  }
#pragma unroll
  for (int off = 32; off; off >>= 1) {
    d0 += __shfl_xor(d0, off); d1 += __shfl_xor(d1, off);
    d2 += __shfl_xor(d2, off); d3 += __shfl_xor(d3, off);
  }
  if (l == 0) {
    float l0 = d0 + gb[0], l1 = d1 + gb[1], l2 = d2 + gb[2], l3 = d3 + gb[3];
    float mx = fmaxf(fmaxf(l0, l1), fmaxf(l2, l3));
    float e0 = __expf(l0 - mx), e1 = __expf(l1 - mx), e2 = __expf(l2 - mx), e3 = __expf(l3 - mx);
    float inv = 1.0f / (e0 + e1 + e2 + e3);
    f32x4 r; r[0] = e0 * inv; r[1] = e1 * inv; r[2] = e2 * inv; r[3] = e3 * inv;
    ((f32x4*)(probs + m * 4))[0] = r;
  }
}

extern "C" void kernel_launch(void* const* d_in, const int* in_sizes, int n_in,
                              void* d_out, int out_size, void* d_ws, size_t ws_size,
                              hipStream_t stream) {
  (void)in_sizes; (void)n_in; (void)out_size; (void)ws_size;
  const float* x_ctx    = (const float*)d_in[0];
  const float* x_tgt    = (const float*)d_in[1];
  const float* enc_Win  = (const float*)d_in[2];
  const float* enc_bin  = (const float*)d_in[3];
  const float* enc_dec  = (const float*)d_in[4];
  const float* enc_Wout = (const float*)d_in[5];
  const float* enc_bout = (const float*)d_in[6];
  const float* enc_gam  = (const float*)d_in[7];
  const float* enc_bet  = (const float*)d_in[8];
  const float* tgt_Win  = (const float*)d_in[9];
  const float* tgt_bin  = (const float*)d_in[10];
  const float* tgt_dec  = (const float*)d_in[11];
  const float* tgt_Wout = (const float*)d_in[12];
  const float* tgt_bout = (const float*)d_in[13];
  const float* tgt_gam  = (const float*)d_in[14];
  const float* tgt_bet  = (const float*)d_in[15];
  const float* gate_W   = (const float*)d_in[16];
  const float* gate_b   = (const float*)d_in[17];
  const float* exp_W    = (const float*)d_in[18];
  const float* exp_b    = (const float*)d_in[19];

  // d_out: pred_z[16M f32] | gate_probs[64K] | z_target[16M f32]
  float* out_pred  = (float*)d_out;
  float* out_probs = out_pred + (size_t)M_TOT * D_DIM;
  float* out_ztgt  = out_probs + (size_t)M_TOT * 4;

  // ws: bf16 weights (24MB liquid + 8MB Wcat) | xb2 (64MB) | sb2 (64MB) = 160MB.
  // ob2 (pre-LN bf16, 64MB) lives in the out_pred slot (free until final MoE).
  char* ws = (char*)d_ws;
  u16* wbTgtIn  = (u16*)ws;
  u16* wbTgtOut = wbTgtIn  + (size_t)3 * 1048576;
  u16* wbEncIn  = wbTgtOut + (size_t)3 * 1048576;
  u16* wbEncOut = wbEncIn  + (size_t)3 * 1048576;
  u16* wbExp    = wbEncOut + (size_t)3 * 1048576;   // Wcat [4096][1024]
  u16* xb2      = wbExp    + (size_t)4 * 1048576;
  u16* sb2      = xb2 + (size_t)M2 * D_DIM;
  u16* ob2      = (u16*)out_pred;
  u16* xbCtx    = xb2 + (size_t)M_TOT * D_DIM;

  auto conv = [&](const float* s, u16* d, size_t n) {
    int n4 = (int)(n / 4);
    conv_kernel<<<(n4 + 255) / 256, 256, 0, stream>>>(s, d, n4);
  };
  conv(tgt_Win,  wbTgtIn,  (size_t)3 * 1048576);
  conv(tgt_Wout, wbTgtOut, (size_t)3 * 1048576);
  conv(enc_Win,  wbEncIn,  (size_t)3 * 1048576);
  conv(enc_Wout, wbEncOut, (size_t)3 * 1048576);
  conv_wexp<<<2048, 256, 0, stream>>>(exp_W, wbExp);
  conv(x_tgt, xb2,   (size_t)M_TOT * D_DIM);
  conv(x_ctx, xbCtx, (size_t)M_TOT * D_DIM);

  // ---- fused liquid stacks (rows 0..16383 = tgt, 16384..32767 = enc/ctx) ----
  int nwg2 = M2 / 128 * 8;   // 2048
  for (int i = 0; i < N_LAYERS; i++) {
    size_t wo = (size_t)i * 1048576;
    gemm97<0><<<nwg2, 256, 0, stream>>>(
        xb2, wbTgtIn + wo, wbEncIn + wo,
        tgt_bin + i * 1024, enc_bin + i * 1024,
        tgt_dec + i * 1024, enc_dec + i * 1024,
        xb2, nullptr, M2 / 128, 3, M_TOT / 128, sb2, nullptr);
    gemm97<1><<<nwg2, 256, 0, stream>>>(
        sb2, wbTgtOut + wo, wbEncOut + wo,
        tgt_bout + i * 1024, enc_bout + i * 1024,
        nullptr, nullptr,
        xb2, nullptr, M2 / 128, 3, M_TOT / 128, ob2, nullptr);
    ln_fused<<<M2, 256, 0, stream>>>(ob2,
        tgt_gam + i * 1024, tgt_bet + i * 1024,
        enc_gam + i * 1024, enc_bet + i * 1024,
        (i == N_LAYERS - 1) ? out_ztgt : nullptr, xb2);
  }

  // ---- MoE head: gate probs, then ONE fused N=4096 GEMM over Wcat ----
  gate_kernel<<<M_TOT / 4, 256, 0, stream>>>(xbCtx, gate_W, gate_b, out_probs);
  int moeWgs = (M_TOT / 128) * 32;   // 4096 (nsh = 5)
  gemm97<5><<<moeWgs, 256, 0, stream>>>(
      xbCtx, wbExp, nullptr,
      exp_b, nullptr, nullptr, nullptr,
      nullptr, out_probs, M_TOT / 128, 5, 1 << 30, nullptr, out_pred);
}

// Round 11
// 761.240 us; speedup vs baseline: 1.0207x; 1.0207x over previous
//
#include <hip/hip_runtime.h>
#include <stdint.h>

#define D_DIM 1024
#define M_TOT 16384        // rows per stream (8*2048)
#define M2 32768           // fused enc+tgt rows
#define N_LAYERS 3
#define NT 16              // K tiles (K=1024 / BK=64)

typedef unsigned short u16;
typedef __attribute__((ext_vector_type(8))) short bf16x8;
typedef __attribute__((ext_vector_type(4))) float f32x4;
typedef __attribute__((ext_vector_type(4))) unsigned short u16x4;
typedef __attribute__((ext_vector_type(8))) unsigned short u16x8;

typedef __attribute__((address_space(1))) void gvoid_t;
typedef __attribute__((address_space(3))) void lvoid_t;

__device__ __forceinline__ float b2f(u16 u) {
  union { unsigned int i; float f; } x; x.i = ((unsigned int)u) << 16; return x.f;
}
__device__ __forceinline__ u16 f2b(float f) {  // RNE f32 -> bf16
  union { float f; unsigned int i; } x; x.f = f;
  unsigned int r = x.i + 0x7fffu + ((x.i >> 16) & 1u);
  return (u16)(r >> 16);
}

__device__ __forceinline__ void gload_lds16(const void* g, void* l) {
  __builtin_amdgcn_global_load_lds((gvoid_t*)(uintptr_t)g,
                                   (lvoid_t*)(unsigned int)(uintptr_t)l, 16, 0, 0);
}

// ---------------------------------------------------------------------------
// m97-exact GEMM engine (R9-verified: 820 TF, 0 bank conflicts, VGPR 56):
// 128x128 tile, BK=64, 256 thr (2x2 waves, 4x4 frags of 16x16x32), SINGLE
// 32KB LDS buffer, plain 2-barrier K-loop, plain C++ LDS reads. Mechanism:
// blocks/CU co-residency gives cross-block DS||MFMA||HBM overlap (m114/m97).
// launch_bounds(256,4): R9-verified sweet spot (5 squeezed VGPR 56->48 and
// regressed ~2% -- R10 evidence).
// B row-major [N x K] (B^T GEMM). Grid: bmT = wg>>nsh, bnT = wg&((1<<nsh)-1).
// EPI 0: outB = bf16(sigmoid(acc+bias) * xfB * decay)
// EPI 1: outB = bf16(acc + bias + xfB)              (pre-LN)
// EPI 5: fused MoE over interleaved Wcat (col n = f*4+e):
//        v = probs[m,e]*(acc + exp_b[e*1024+f]); nibble shfl-sum over e;
//        lane (lm&3)==0 writes outF[m][f]  (full f32 combine).
// ---------------------------------------------------------------------------
template <int EPI>
__global__ __launch_bounds__(256, 4) void gemm97(
    const u16* __restrict__ A,
    const u16* __restrict__ B_a, const u16* __restrict__ B_b,
    const float* __restrict__ bias_a, const float* __restrict__ bias_b,
    const float* __restrict__ dec_a, const float* __restrict__ dec_b,
    const u16* __restrict__ xfB, const float* __restrict__ probs,
    int mTiles, int nsh, int split,
    u16* __restrict__ outB, float* __restrict__ outF)
{
  __shared__ __align__(128) u16 lds[16384];   // 32KB: A[128][64] @0, B @16KB
  const char* ldsc = (const char*)lds;
  int t = threadIdx.x;
  int wid = t >> 6, l = t & 63;
  int wm = wid >> 1, wn = wid & 1;            // 2x2 waves; wave tile 64x64
  int lm = l & 15, g = l >> 4;

  int nwg = mTiles << nsh;
  int orig = blockIdx.x;
  int wg = (orig & 7) * (nwg >> 3) + (orig >> 3);   // bijective (nwg % 8 == 0)
  int bmT = wg >> nsh, bnT = wg & ((1 << nsh) - 1);
  int bm0 = bmT << 7, bn0 = bnT << 7;

  const u16*  Bm   = (bmT < split) ? B_a   : B_b;
  const float* bias = (bmT < split) ? bias_a : bias_b;
  const float* dec  = (bmT < split) ? dec_a  : dec_b;

  // staging: 8 threads per 128B row (16B each), 32 rows/round, 4 rounds/matrix.
  // physical chunk q holds logical chunk q ^ (row&7)  (pre-swizzled source).
  int rowS = t >> 3;                          // 0..31
  int colE = ((t & 7) ^ (rowS & 7)) << 3;     // element col within 64-elem row
  const u16* pA = A  + (size_t)(bm0 + rowS) * D_DIM + colE;
  const u16* pB = Bm + (size_t)(bn0 + rowS) * D_DIM + colE;
  u16* dW = lds + wid * 512;                  // wave-uniform dst (lane*16B implicit)

  f32x4 acc[4][4];
#pragma unroll
  for (int mi = 0; mi < 4; mi++)
#pragma unroll
    for (int ni = 0; ni < 4; ni++) acc[mi][ni] = 0.0f;

  // read-side swizzled k-col byte offsets: logical chunk = ks*4+g, ^ (lm&7)
  unsigned kc0 = (unsigned)(((0 * 4 + g) ^ (lm & 7)) << 4);
  unsigned kc1 = (unsigned)(((1 * 4 + g) ^ (lm & 7)) << 4);
  unsigned rbA = (unsigned)((wm * 64 + lm) * 128);
  unsigned rbB = (unsigned)(16384 + (wn * 64 + lm) * 128);

  for (int kt = 0; kt < NT; ++kt) {
    // ---- stage tile kt (single buffer) ----
    {
      const u16* a0 = pA + kt * 64;
      const u16* b0 = pB + kt * 64;
#pragma unroll
      for (int r = 0; r < 4; r++) {
        gload_lds16(a0 + (size_t)r * 32 * D_DIM, dW + r * 2048);
        gload_lds16(b0 + (size_t)r * 32 * D_DIM, dW + 8192 + r * 2048);
      }
    }
    __syncthreads();    // compiler: s_waitcnt vmcnt(0) lgkmcnt(0) + s_barrier
    // ---- compute tile kt ----
#pragma unroll
    for (int ks = 0; ks < 2; ks++) {
      unsigned kc = ks ? kc1 : kc0;
      bf16x8 av[4], bv[4];
#pragma unroll
      for (int mi = 0; mi < 4; mi++)
        av[mi] = *(const bf16x8*)(ldsc + rbA + mi * 2048 + kc);
#pragma unroll
      for (int ni = 0; ni < 4; ni++)
        bv[ni] = *(const bf16x8*)(ldsc + rbB + ni * 2048 + kc);
#pragma unroll
      for (int mi = 0; mi < 4; mi++)
#pragma unroll
        for (int ni = 0; ni < 4; ni++)
          acc[mi][ni] = __builtin_amdgcn_mfma_f32_16x16x32_bf16(av[mi], bv[ni], acc[mi][ni], 0, 0, 0);
    }
    __syncthreads();    // reads done before next stage overwrites
  }

  // ---- epilogue ----  m = bm0+wm*64+mi*16+g*4+j, n = bn0+wn*64+ni*16+lm
  int nidx[4]; float bia[4], dcv[4];
#pragma unroll
  for (int ni = 0; ni < 4; ni++) {
    nidx[ni] = bn0 + wn * 64 + ni * 16 + lm;
    if (EPI == 5) bia[ni] = bias[(nidx[ni] & 3) * 1024 + (nidx[ni] >> 2)];
    else          bia[ni] = bias[nidx[ni]];
    dcv[ni] = (EPI == 0) ? dec[nidx[ni]] : 0.0f;
  }
#pragma unroll
  for (int mi = 0; mi < 4; mi++)
#pragma unroll
    for (int j = 0; j < 4; j++) {
      size_t m = (size_t)bm0 + wm * 64 + mi * 16 + g * 4 + j;
      if (EPI == 0) {
        const u16* xr = xfB + m * D_DIM;
        u16* orow = outB + m * D_DIM;
#pragma unroll
        for (int ni = 0; ni < 4; ni++) {
          float v = acc[mi][ni][j] + bia[ni];
          float gt = 1.0f / (1.0f + __expf(-v));
          orow[nidx[ni]] = f2b(gt * b2f(xr[nidx[ni]]) * dcv[ni]);
        }
      } else if (EPI == 1) {
        const u16* xr = xfB + m * D_DIM;
        u16* orow = outB + m * D_DIM;
#pragma unroll
        for (int ni = 0; ni < 4; ni++)
          orow[nidx[ni]] = f2b(acc[mi][ni][j] + bia[ni] + b2f(xr[nidx[ni]]));
      } else {
        // EPI 5: e = nidx&3 == lm&3 (bn0, wn*64, ni*16 all multiples of 4)
        float p = probs[m * 4 + (lm & 3)];
        float* orow = outF + m * D_DIM;
#pragma unroll
        for (int ni = 0; ni < 4; ni++) {
          float v = p * (acc[mi][ni][j] + bia[ni]);
          v += __shfl_xor(v, 1);
          v += __shfl_xor(v, 2);
          if ((lm & 3) == 0) orow[nidx[ni] >> 2] = v;
        }
      }
    }
}

// Fused-stack LayerNorm over D=1024 (rows<M_TOT -> tgt params, else enc).
__global__ __launch_bounds__(256) void ln_fused(const u16* __restrict__ src,
                                                const float* __restrict__ gamT,
                                                const float* __restrict__ betT,
                                                const float* __restrict__ gamE,
                                                const float* __restrict__ betE,
                                                float* __restrict__ dstF,
                                                u16* __restrict__ dstB) {
  size_t row = blockIdx.x;
  const float* gamma = (row < M_TOT) ? gamT : gamE;
  const float* beta  = (row < M_TOT) ? betT : betE;
  int t = threadIdx.x, w = t >> 6, l = t & 63;
  u16x4 vb = ((const u16x4*)(src + row * D_DIM))[t];
  float v[4];
#pragma unroll
  for (int i = 0; i < 4; i++) v[i] = b2f(vb[i]);
  float s = v[0] + v[1] + v[2] + v[3];
  float qs = v[0]*v[0] + v[1]*v[1] + v[2]*v[2] + v[3]*v[3];
#pragma unroll
  for (int off = 32; off; off >>= 1) { s += __shfl_xor(s, off); qs += __shfl_xor(qs, off); }
  __shared__ float red[8];
  if (l == 0) { red[w] = s; red[4 + w] = qs; }
  __syncthreads();
  s = red[0] + red[1] + red[2] + red[3];
  qs = red[4] + red[5] + red[6] + red[7];
  float mu = s * (1.0f / 1024.0f);
  float var = qs * (1.0f / 1024.0f) - mu * mu;
  float inv = rsqrtf(var + 1e-5f);
  f32x4 gm = ((const f32x4*)gamma)[t], b = ((const f32x4*)beta)[t];
  f32x4 y; u16x4 yb;
#pragma unroll
  for (int i = 0; i < 4; i++) { y[i] = (v[i] - mu) * inv * gm[i] + b[i]; yb[i] = f2b(y[i]); }
  ((u16x4*)(dstB + row * D_DIM))[t] = yb;
  if (dstF != nullptr && row < M_TOT) ((f32x4*)(dstF + row * D_DIM))[t] = y;
}

// f32 -> bf16 elementwise
__global__ void conv_kernel(const float* __restrict__ src, u16* __restrict__ dst, int n4) {
  int i = blockIdx.x * 256 + threadIdx.x;
  if (i >= n4) return;
  f32x4 v = ((const f32x4*)src)[i];
  u16x4 o;
#pragma unroll
  for (int j = 0; j < 4; j++) o[j] = f2b(v[j]);
  ((u16x4*)dst)[i] = o;
}

// exp_W [4][1024][1024] f32 -> Wcat bf16 [4096][1024], row (f*4+e) = W_e[f][:]
__global__ void conv_wexp(const float* __restrict__ src, u16* __restrict__ dst) {
  int c = blockIdx.x * 256 + threadIdx.x;    // 524288 threads, 8 elems each
  int k8 = c & 127;
  int e  = (c >> 7) & 3;
  int f  = c >> 9;
  const float* s = src + ((size_t)e << 20) + (size_t)f * 1024 + k8 * 8;
  f32x4 v0 = ((const f32x4*)s)[0];
  f32x4 v1 = ((const f32x4*)s)[1];
  u16x8 o;
#pragma unroll
  for (int i = 0; i < 4; i++) { o[i] = f2b(v0[i]); o[4 + i] = f2b(v1[i]); }
  *(u16x8*)(dst + ((size_t)(f * 4 + e) << 10) + k8 * 8) = o;
}

// Gate: logits + softmax -> probs[m,0..3]. One wave per row.
__global__ __launch_bounds__(256) void gate_kernel(const u16* __restrict__ zb,
                                                   const float* __restrict__ gW,
                                                   const float* __restrict__ gb,
                                                   float* __restrict__ probs) {
  __shared__ float sW[4096];
  int t = threadIdx.x;
#pragma unroll
  for (int c = 0; c < 4; c++) ((f32x4*)sW)[c * 256 + t] = ((const f32x4*)gW)[c * 256 + t];
  __syncthreads();
  int w = t >> 6, l = t & 63;
  size_t m = (size_t)blockIdx.x * 4 + w;
  const u16* zr = zb + m * D_DIM;
  float d0 = 0, d1 = 0, d2 = 0, d3 = 0;
#pragma unroll
  for (int c = 0; c < 4; c++) {
    int k = l * 4 + c * 256;
    u16x4 zv = *(const u16x4*)(zr + k);
    f32x4 w0 = *(const f32x4*)&sW[k];
    f32x4 w1 = *(const f32x4*)&sW[1024 + k];
    f32x4 w2 = *(const f32x4*)&sW[2048 + k];
    f32x4 w3 = *(const f32x4*)&sW[3072 + k];
#pragma unroll
    for (int i = 0; i < 4; i++) {
      float zf = b2f(zv[i]);
      d0 += zf * w0[i]; d1 += zf * w1[i]; d2 += zf * w2[i]; d3 += zf * w3[i];
    }
  }
#pragma unroll
  for (int off = 32; off; off >>= 1) {
    d0 += __shfl_xor(d0, off); d1 += __shfl_xor(d1, off);
    d2 += __shfl_xor(d2, off); d3 += __shfl_xor(d3, off);
  }
  if (l == 0) {
    float l0 = d0 + gb[0], l1 = d1 + gb[1], l2 = d2 + gb[2], l3 = d3 + gb[3];
    float mx = fmaxf(fmaxf(l0, l1), fmaxf(l2, l3));
    float e0 = __expf(l0 - mx), e1 = __expf(l1 - mx), e2 = __expf(l2 - mx), e3 = __expf(l3 - mx);
    float inv = 1.0f / (e0 + e1 + e2 + e3);
    f32x4 r; r[0] = e0 * inv; r[1] = e1 * inv; r[2] = e2 * inv; r[3] = e3 * inv;
    ((f32x4*)(probs + m * 4))[0] = r;
  }
}

extern "C" void kernel_launch(void* const* d_in, const int* in_sizes, int n_in,
                              void* d_out, int out_size, void* d_ws, size_t ws_size,
                              hipStream_t stream) {
  (void)in_sizes; (void)n_in; (void)out_size; (void)ws_size;
  const float* x_ctx    = (const float*)d_in[0];
  const float* x_tgt    = (const float*)d_in[1];
  const float* enc_Win  = (const float*)d_in[2];
  const float* enc_bin  = (const float*)d_in[3];
  const float* enc_dec  = (const float*)d_in[4];
  const float* enc_Wout = (const float*)d_in[5];
  const float* enc_bout = (const float*)d_in[6];
  const float* enc_gam  = (const float*)d_in[7];
  const float* enc_bet  = (const float*)d_in[8];
  const float* tgt_Win  = (const float*)d_in[9];
  const float* tgt_bin  = (const float*)d_in[10];
  const float* tgt_dec  = (const float*)d_in[11];
  const float* tgt_Wout = (const float*)d_in[12];
  const float* tgt_bout = (const float*)d_in[13];
  const float* tgt_gam  = (const float*)d_in[14];
  const float* tgt_bet  = (const float*)d_in[15];
  const float* gate_W   = (const float*)d_in[16];
  const float* gate_b   = (const float*)d_in[17];
  const float* exp_W    = (const float*)d_in[18];
  const float* exp_b    = (const float*)d_in[19];

  // d_out: pred_z[16M f32] | gate_probs[64K] | z_target[16M f32]
  float* out_pred  = (float*)d_out;
  float* out_probs = out_pred + (size_t)M_TOT * D_DIM;
  float* out_ztgt  = out_probs + (size_t)M_TOT * 4;

  // ws: bf16 weights (24MB liquid + 8MB Wcat) | xb2 (64MB) | sb2 (64MB) = 160MB.
  // ob2 (pre-LN bf16, 64MB) lives in the out_pred slot (free until final MoE).
  char* ws = (char*)d_ws;
  u16* wbTgtIn  = (u16*)ws;
  u16* wbTgtOut = wbTgtIn  + (size_t)3 * 1048576;
  u16* wbEncIn  = wbTgtOut + (size_t)3 * 1048576;
  u16* wbEncOut = wbEncIn  + (size_t)3 * 1048576;
  u16* wbExp    = wbEncOut + (size_t)3 * 1048576;   // Wcat [4096][1024]
  u16* xb2      = wbExp    + (size_t)4 * 1048576;
  u16* sb2      = xb2 + (size_t)M2 * D_DIM;
  u16* ob2      = (u16*)out_pred;
  u16* xbCtx    = xb2 + (size_t)M_TOT * D_DIM;

  auto conv = [&](const float* s, u16* d, size_t n) {
    int n4 = (int)(n / 4);
    conv_kernel<<<(n4 + 255) / 256, 256, 0, stream>>>(s, d, n4);
  };
  conv(tgt_Win,  wbTgtIn,  (size_t)3 * 1048576);
  conv(tgt_Wout, wbTgtOut, (size_t)3 * 1048576);
  conv(enc_Win,  wbEncIn,  (size_t)3 * 1048576);
  conv(enc_Wout, wbEncOut, (size_t)3 * 1048576);
  conv_wexp<<<2048, 256, 0, stream>>>(exp_W, wbExp);
  conv(x_tgt, xb2,   (size_t)M_TOT * D_DIM);
  conv(x_ctx, xbCtx, (size_t)M_TOT * D_DIM);

  // ---- fused liquid stacks (rows 0..16383 = tgt, 16384..32767 = enc/ctx) ----
  int nwg2 = M2 / 128 * 8;   // 2048
  for (int i = 0; i < N_LAYERS; i++) {
    size_t wo = (size_t)i * 1048576;
    gemm97<0><<<nwg2, 256, 0, stream>>>(
        xb2, wbTgtIn + wo, wbEncIn + wo,
        tgt_bin + i * 1024, enc_bin + i * 1024,
        tgt_dec + i * 1024, enc_dec + i * 1024,
        xb2, nullptr, M2 / 128, 3, M_TOT / 128, sb2, nullptr);
    gemm97<1><<<nwg2, 256, 0, stream>>>(
        sb2, wbTgtOut + wo, wbEncOut + wo,
        tgt_bout + i * 1024, enc_bout + i * 1024,
        nullptr, nullptr,
        xb2, nullptr, M2 / 128, 3, M_TOT / 128, ob2, nullptr);
    ln_fused<<<M2, 256, 0, stream>>>(ob2,
        tgt_gam + i * 1024, tgt_bet + i * 1024,
        enc_gam + i * 1024, enc_bet + i * 1024,
        (i == N_LAYERS - 1) ? out_ztgt : nullptr, xb2);
  }

  // ---- MoE head: gate probs, then ONE fused N=4096 GEMM over Wcat ----
  gate_kernel<<<M_TOT / 4, 256, 0, stream>>>(xbCtx, gate_W, gate_b, out_probs);
  int moeWgs = (M_TOT / 128) * 32;   // 4096 (nsh = 5)
  gemm97<5><<<moeWgs, 256, 0, stream>>>(
      xbCtx, wbExp, nullptr,
      exp_b, nullptr, nullptr, nullptr,
      nullptr, out_probs, M_TOT / 128, 5, 1 << 30, nullptr, out_pred);
}